// Round 11
// baseline (109.951 us; speedup 1.0000x reference)
//
#include <hip/hip_runtime.h>

#define NN 4096
#define DD 512
#define CP 128          // classes padded to 128 (pad classes: cnt=0, G=0 -> vanish)
#define MT 16           // rows per kB block
#define NBB 256         // kB grid
#define LROWS 64        // kA LDS-staged rows per class (tail handled from global)

// ws float-word offsets (NEG/DONE zeroed by kA block 0)
#define NEG   0
#define DONE  1
#define D_OFF 16
#define CNTF_OFF (16 + NN)
#define GB_OFF_W (16 + NN + CP)   // 16B-aligned; bf16 G[CP][DD]

typedef __attribute__((ext_vector_type(8))) short bf16x8;
typedef __attribute__((ext_vector_type(4))) float f32x4;

static __device__ inline unsigned short f2bf(float f) {
    unsigned int u = __float_as_uint(f);
    unsigned int r = u + 0x7fffu + ((u >> 16) & 1u);   // round-to-nearest-even
    return (unsigned short)(r >> 16);
}

// kA: one block per class (512 thr). Ballot-scan labels; stage member rows into
// LDS once via 16 hoisted predicated loads (full MLP depth); norms and gather
// run from LDS. Tail rows (>LROWS, never expected) from global.
__global__ __launch_bounds__(512, 1) void kA(const float* __restrict__ img,
                                             const int* __restrict__ labels,
                                             float* __restrict__ ws) {
    __shared__ __align__(16) float lrows[LROWS * DD];   // 128 KB
    __shared__ int   wlist[8][32];
    __shared__ int   wcnt[8];
    __shared__ int   soff[9];
    __shared__ int   flat[256];
    __shared__ float sinv[256];
    int c = blockIdx.x, t = threadIdx.x, w = t >> 6, l = t & 63;

    if (c == 0 && t == 0) { ws[NEG] = 0.0f; ((int*)ws)[DONE] = 0; }

    // scan: wave w scans rows [w*512, (w+1)*512)
    int cnt = 0;
    for (int it = 0; it < 8; ++it) {
        int row = (w << 9) + (it << 6) + l;
        int lab = labels[row];
        unsigned long long m = __ballot(lab == c);
        if (lab == c) {
            int pos = cnt + (int)__popcll(m & ((1ull << l) - 1ull));
            if (pos < 32) wlist[w][pos] = row;   // per-stripe cap, never binds
        }
        cnt += (int)__popcll(m);
    }
    if (l == 0) wcnt[w] = cnt < 32 ? cnt : 32;
    __syncthreads();
    if (t == 0) {
        int o = 0;
        #pragma unroll
        for (int i = 0; i < 8; ++i) { soff[i] = o; o += wcnt[i]; }
        soff[8] = o;
    }
    __syncthreads();
    int n = soff[8];
    for (int s = l; s < wcnt[w]; s += 64) flat[soff[w] + s] = wlist[w][s];
    __syncthreads();

    int nl = n < LROWS ? n : LROWS;
    const float4* img4 = (const float4*)img;
    float4* lr4 = (float4*)lrows;

    // stage rows -> LDS: 16 hoisted predicated loads (all in flight), then writes
    {
        int total = nl * 128;
        float4 tv[16];
        #pragma unroll
        for (int k = 0; k < 16; ++k) {
            int idx = t + (k << 9);
            if (idx < total) tv[k] = img4[(size_t)flat[idx >> 7] * 128 + (idx & 127)];
        }
        #pragma unroll
        for (int k = 0; k < 16; ++k) {
            int idx = t + (k << 9);
            if (idx < total) lr4[idx] = tv[k];
        }
    }
    __syncthreads();

    // norms: wave per row-slot (LDS for staged rows, global for tail)
    for (int s = w; s < n; s += 8) {
        float4 v0, v1;
        if (s < nl) { v0 = lr4[s * 128 + l]; v1 = lr4[s * 128 + 64 + l]; }
        else { int j = flat[s]; v0 = img4[(size_t)j * 128 + l]; v1 = img4[(size_t)j * 128 + 64 + l]; }
        float ss = v0.x*v0.x + v0.y*v0.y + v0.z*v0.z + v0.w*v0.w
                 + v1.x*v1.x + v1.y*v1.y + v1.z*v1.z + v1.w*v1.w;
        #pragma unroll
        for (int o = 32; o >= 1; o >>= 1) ss += __shfl_xor(ss, o);
        if (l == 0) sinv[s] = rsqrtf(ss);
    }
    __syncthreads();

    // gather: thread t owns column t (LDS reads, conflict-free)
    float acc = 0.f;
    #pragma unroll 8
    for (int s = 0; s < nl; ++s) acc += lrows[s * DD + t] * sinv[s];
    for (int s = nl; s < n; ++s) acc += img[(size_t)flat[s] * DD + t] * sinv[s];

    unsigned short* gbf = (unsigned short*)(ws + GB_OFF_W);
    gbf[(size_t)c * DD + t] = f2bf(acc);
    if (t == 0) ws[CNTF_OFF + c] = (float)n;
}

// kB: 256 blocks x 16 rows, 512 threads (8 waves, 2/SIMD), 1 block/CU (145KB LDS).
// ALL global loads (8 img/txt float4 + 16 G int4 per lane) issued before any math;
// norm math covers load latency. MFMA: 1 fragment/wave (16 classes). Epilogue and
// done-counter finalize are the verified R8 math adapted to 8 waves.
__global__ __launch_bounds__(512, 1) void kB(const float* __restrict__ img,
                                             const float* __restrict__ txt,
                                             float* __restrict__ ws,
                                             float* __restrict__ out) {
    __shared__ __align__(16) unsigned char As[MT * 1024];   // 16 KB  bf16 txtN tile (swizzled)
    __shared__ __align__(16) unsigned char Bs[CP * 1024];   // 128 KB bf16 G (swizzled)
    __shared__ float cnts[CP];
    __shared__ float part[8][MT];
    __shared__ float Ss[MT];
    __shared__ float wred[8];
    __shared__ float sneg;
    __shared__ int   sdone;

    int t = threadIdx.x, w = t >> 6, l = t & 63;
    int b = blockIdx.x;
    int row0 = b * MT;
    int* wsi = (int*)ws;

    // ---- issue ALL global loads first (24 x 16B per lane in flight)
    float4 iA0[2], iA1[2], tB0[2], tB1[2];
    #pragma unroll
    for (int i = 0; i < 2; ++i) {
        int row = row0 + 2 * w + i;
        const float4* i4  = (const float4*)(img + (size_t)row * DD);
        const float4* t4p = (const float4*)(txt + (size_t)row * DD);
        iA0[i] = i4[l];  iA1[i] = i4[l + 64];
        tB0[i] = t4p[l]; tB1[i] = t4p[l + 64];
    }
    int4 gr[16];
    const int4* gB = (const int4*)(ws + GB_OFF_W);   // 128 rows x 64 int4 = 8192
    #pragma unroll
    for (int s = 0; s < 16; ++s) gr[s] = gr[s] = gB[s * 512 + t];
    if (t < CP) cnts[t] = ws[CNTF_OFF + t];

    // ---- phase A math: norms, d_i, bf16 txtN -> As (swizzled); covers latency
    #pragma unroll
    for (int i = 0; i < 2; ++i) {
        int lr  = 2 * w + i;
        int row = row0 + lr;
        float4 a0 = iA0[i], a1 = iA1[i], b0 = tB0[i], b1 = tB1[i];
        float ssi = a0.x*a0.x + a0.y*a0.y + a0.z*a0.z + a0.w*a0.w
                  + a1.x*a1.x + a1.y*a1.y + a1.z*a1.z + a1.w*a1.w;
        float sst = b0.x*b0.x + b0.y*b0.y + b0.z*b0.z + b0.w*b0.w
                  + b1.x*b1.x + b1.y*b1.y + b1.z*b1.z + b1.w*b1.w;
        float dot = a0.x*b0.x + a0.y*b0.y + a0.z*b0.z + a0.w*b0.w
                  + a1.x*b1.x + a1.y*b1.y + a1.z*b1.z + a1.w*b1.w;
        #pragma unroll
        for (int o = 32; o >= 1; o >>= 1) {
            ssi += __shfl_xor(ssi, o);
            sst += __shfl_xor(sst, o);
            dot += __shfl_xor(dot, o);
        }
        float inv_t = rsqrtf(sst);
        ushort4 s0, s1;
        s0.x = f2bf(b0.x*inv_t); s0.y = f2bf(b0.y*inv_t);
        s0.z = f2bf(b0.z*inv_t); s0.w = f2bf(b0.w*inv_t);
        s1.x = f2bf(b1.x*inv_t); s1.y = f2bf(b1.y*inv_t);
        s1.z = f2bf(b1.z*inv_t); s1.w = f2bf(b1.w*inv_t);
        int swz = (lr & 7) << 4;
        *(ushort4*)&As[lr * 1024 + ((8 * l) ^ swz)]       = s0;
        *(ushort4*)&As[lr * 1024 + 512 + ((8 * l) ^ swz)] = s1;
        if (l == 0) {
            float inv_i = rsqrtf(ssi);
            ws[D_OFF + row] = dot * inv_i * inv_t;
        }
    }

    // ---- write G -> Bs (swizzled): gr[s] is class c = 8s + w, int4-col l
    #pragma unroll
    for (int s = 0; s < 16; ++s) {
        int c = 8 * s + w;
        *(int4*)&Bs[c * 1024 + ((l * 16) ^ ((c & 7) << 4))] = gr[s];
    }
    __syncthreads();

    // ---- MFMA: each wave computes rows 0..15 x classes [16w, 16w+16)
    f32x4 acc = {0.f, 0.f, 0.f, 0.f};
    int arow = l & 15, kq = l >> 4;
    int aswz = (arow & 7) << 4;
    int cA = 16 * w + arow;
    int aoffA = cA * 1024, aswzA = (cA & 7) << 4;
    #pragma unroll
    for (int ch = 0; ch < 16; ++ch) {
        int kb = ch * 64 + kq * 16;
        bf16x8 af = *(const bf16x8*)&As[arow * 1024 + (kb ^ aswz)];
        bf16x8 bf = *(const bf16x8*)&Bs[aoffA + (kb ^ aswzA)];
        acc = __builtin_amdgcn_mfma_f32_16x16x32_bf16(af, bf, acc, 0, 0, 0);
    }

    // ---- epilogue: S per row (16-lane reduce per wave, cross-wave via part)
    float rsum[4];
    #pragma unroll
    for (int r = 0; r < 4; ++r) {
        float s = acc[r];
        #pragma unroll
        for (int o = 1; o < 16; o <<= 1) s += __shfl_xor(s, o);
        rsum[r] = s;
    }
    if ((l & 15) == 0) {
        #pragma unroll
        for (int r = 0; r < 4; ++r) part[w][kq * 4 + r] = rsum[r];
    }
    __syncthreads();
    if (t < MT) {
        float ssum = 0.f;
        #pragma unroll
        for (int g = 0; g < 8; ++g) ssum += part[g][t];
        Ss[t] = ssum;
    }
    __syncthreads();
    float p;
    {
        float e0 = 0.f;
        #pragma unroll
        for (int r = 0; r < 4; ++r) e0 += __expf(Ss[kq * 4 + r] - acc[r]);
        p = cnts[cA] * e0;
    }
    #pragma unroll
    for (int o = 32; o >= 1; o >>= 1) p += __shfl_xor(p, o);
    if (l == 0) wred[w] = p;
    __syncthreads();
    if (t == 0) {
        float ptot = 0.f;
        #pragma unroll
        for (int g = 0; g < 8; ++g) ptot += wred[g];
        atomicAdd(ws + NEG, ptot);
        __threadfence();
        int old = atomicAdd(wsi + DONE, 1);
        sdone = (old == NBB - 1);
        if (sdone) sneg = atomicAdd(ws + NEG, 0.0f);   // coherent read-back
    }
    __syncthreads();
    if (sdone) {
        __threadfence();   // acquire before reading cross-block D
        float neg = sneg;
        float s = 0.f;
        #pragma unroll 4
        for (int i = t; i < NN; i += 512) {
            float dv = ws[D_OFF + i];
            s += logf(__expf(dv) + neg) - dv;
        }
        #pragma unroll
        for (int o = 32; o >= 1; o >>= 1) s += __shfl_xor(s, o);
        __syncthreads();
        if (l == 0) wred[w] = s;
        __syncthreads();
        if (t == 0) {
            float stot = 0.f;
            #pragma unroll
            for (int g = 0; g < 8; ++g) stot += wred[g];
            out[0] = stot;
        }
    }
}

extern "C" void kernel_launch(void* const* d_in, const int* in_sizes, int n_in,
                              void* d_out, int out_size, void* d_ws, size_t ws_size,
                              hipStream_t stream) {
    const float* img  = (const float*)d_in[0];
    const float* txt  = (const float*)d_in[1];
    const int* labels = (const int*)d_in[2];
    float* ws  = (float*)d_ws;
    float* out = (float*)d_out;

    kA<<<CP,  512, 0, stream>>>(img, labels, ws);
    kB<<<NBB, 512, 0, stream>>>(img, txt, ws, out);
}

// Round 12
// 102.765 us; speedup vs baseline: 1.0699x; 1.0699x over previous
//
#include <hip/hip_runtime.h>

#define NN 4096
#define DD 512
#define CP 128          // classes padded to 128 (pad classes: cnt=0, G=0 -> vanish)
#define MT 16           // rows per kB block
#define NBB 256         // kB grid
#define LROWS 64        // kA LDS-staged rows per class (tail handled from global)

// ws float-word offsets (NEG/DONE zeroed by kA block 0)
#define NEG   0
#define DONE  1
#define D_OFF 16
#define CNTF_OFF (16 + NN)
#define GB_OFF_W (16 + NN + CP)   // 16B-aligned; bf16 G[CP][DD]

typedef __attribute__((ext_vector_type(8))) short bf16x8;
typedef __attribute__((ext_vector_type(4))) float f32x4;

static __device__ inline unsigned short f2bf(float f) {
    unsigned int u = __float_as_uint(f);
    unsigned int r = u + 0x7fffu + ((u >> 16) & 1u);   // round-to-nearest-even
    return (unsigned short)(r >> 16);
}

// kA: one block per class (512 thr). Ballot-scan labels; stage member rows into
// LDS once (simple grid-stride loop — R10-verified, no scratch spill); norms and
// gather run from LDS. Tail rows (>LROWS, never expected) from global.
__global__ __launch_bounds__(512, 1) void kA(const float* __restrict__ img,
                                             const int* __restrict__ labels,
                                             float* __restrict__ ws) {
    __shared__ __align__(16) float lrows[LROWS * DD];   // 128 KB
    __shared__ int   wlist[8][32];
    __shared__ int   wcnt[8];
    __shared__ int   soff[9];
    __shared__ int   flat[256];
    __shared__ float sinv[256];
    int c = blockIdx.x, t = threadIdx.x, w = t >> 6, l = t & 63;

    if (c == 0 && t == 0) { ws[NEG] = 0.0f; ((int*)ws)[DONE] = 0; }

    // scan: wave w scans rows [w*512, (w+1)*512)
    int cnt = 0;
    for (int it = 0; it < 8; ++it) {
        int row = (w << 9) + (it << 6) + l;
        int lab = labels[row];
        unsigned long long m = __ballot(lab == c);
        if (lab == c) {
            int pos = cnt + (int)__popcll(m & ((1ull << l) - 1ull));
            if (pos < 32) wlist[w][pos] = row;   // per-stripe cap, never binds
        }
        cnt += (int)__popcll(m);
    }
    if (l == 0) wcnt[w] = cnt < 32 ? cnt : 32;
    __syncthreads();
    if (t == 0) {
        int o = 0;
        #pragma unroll
        for (int i = 0; i < 8; ++i) { soff[i] = o; o += wcnt[i]; }
        soff[8] = o;
    }
    __syncthreads();
    int n = soff[8];
    for (int s = l; s < wcnt[w]; s += 64) flat[soff[w] + s] = wlist[w][s];
    __syncthreads();

    int nl = n < LROWS ? n : LROWS;
    const float4* img4 = (const float4*)img;
    float4* lr4 = (float4*)lrows;

    // stage rows -> LDS (coalesced grid-stride; no register array, no spill)
    for (int idx = t; idx < nl * 128; idx += 512) {
        int r = idx >> 7, c4 = idx & 127;
        lr4[r * 128 + c4] = img4[(size_t)flat[r] * 128 + c4];
    }
    __syncthreads();

    // norms: wave per row-slot (LDS for staged rows, global for tail)
    for (int s = w; s < n; s += 8) {
        float4 v0, v1;
        if (s < nl) { v0 = lr4[s * 128 + l]; v1 = lr4[s * 128 + 64 + l]; }
        else { int j = flat[s]; v0 = img4[(size_t)j * 128 + l]; v1 = img4[(size_t)j * 128 + 64 + l]; }
        float ss = v0.x*v0.x + v0.y*v0.y + v0.z*v0.z + v0.w*v0.w
                 + v1.x*v1.x + v1.y*v1.y + v1.z*v1.z + v1.w*v1.w;
        #pragma unroll
        for (int o = 32; o >= 1; o >>= 1) ss += __shfl_xor(ss, o);
        if (l == 0) sinv[s] = rsqrtf(ss);
    }
    __syncthreads();

    // gather: thread t owns column t (LDS reads, conflict-free)
    float acc = 0.f;
    #pragma unroll 8
    for (int s = 0; s < nl; ++s) acc += lrows[s * DD + t] * sinv[s];
    for (int s = nl; s < n; ++s) acc += img[(size_t)flat[s] * DD + t] * sinv[s];

    unsigned short* gbf = (unsigned short*)(ws + GB_OFF_W);
    gbf[(size_t)c * DD + t] = f2bf(acc);
    if (t == 0) ws[CNTF_OFF + c] = (float)n;
}

// kB: 256 blocks x 16 rows, 512 threads (8 waves, 2/SIMD), 1 block/CU (145KB LDS).
// ALL global loads (8 img/txt float4 + 16 G int4 per lane) issued before any math;
// norm math covers load latency. MFMA: 1 fragment/wave (16 classes). R11-verified.
__global__ __launch_bounds__(512, 1) void kB(const float* __restrict__ img,
                                             const float* __restrict__ txt,
                                             float* __restrict__ ws,
                                             float* __restrict__ out) {
    __shared__ __align__(16) unsigned char As[MT * 1024];   // 16 KB  bf16 txtN tile (swizzled)
    __shared__ __align__(16) unsigned char Bs[CP * 1024];   // 128 KB bf16 G (swizzled)
    __shared__ float cnts[CP];
    __shared__ float part[8][MT];
    __shared__ float Ss[MT];
    __shared__ float wred[8];
    __shared__ float sneg;
    __shared__ int   sdone;

    int t = threadIdx.x, w = t >> 6, l = t & 63;
    int b = blockIdx.x;
    int row0 = b * MT;
    int* wsi = (int*)ws;

    // ---- issue ALL global loads first (24 x 16B per lane in flight)
    float4 iA0[2], iA1[2], tB0[2], tB1[2];
    #pragma unroll
    for (int i = 0; i < 2; ++i) {
        int row = row0 + 2 * w + i;
        const float4* i4  = (const float4*)(img + (size_t)row * DD);
        const float4* t4p = (const float4*)(txt + (size_t)row * DD);
        iA0[i] = i4[l];  iA1[i] = i4[l + 64];
        tB0[i] = t4p[l]; tB1[i] = t4p[l + 64];
    }
    int4 gr[16];
    const int4* gB = (const int4*)(ws + GB_OFF_W);   // 128 rows x 64 int4 = 8192
    #pragma unroll
    for (int s = 0; s < 16; ++s) gr[s] = gB[s * 512 + t];
    if (t < CP) cnts[t] = ws[CNTF_OFF + t];

    // ---- phase A math: norms, d_i, bf16 txtN -> As (swizzled); covers latency
    #pragma unroll
    for (int i = 0; i < 2; ++i) {
        int lr  = 2 * w + i;
        int row = row0 + lr;
        float4 a0 = iA0[i], a1 = iA1[i], b0 = tB0[i], b1 = tB1[i];
        float ssi = a0.x*a0.x + a0.y*a0.y + a0.z*a0.z + a0.w*a0.w
                  + a1.x*a1.x + a1.y*a1.y + a1.z*a1.z + a1.w*a1.w;
        float sst = b0.x*b0.x + b0.y*b0.y + b0.z*b0.z + b0.w*b0.w
                  + b1.x*b1.x + b1.y*b1.y + b1.z*b1.z + b1.w*b1.w;
        float dot = a0.x*b0.x + a0.y*b0.y + a0.z*b0.z + a0.w*b0.w
                  + a1.x*b1.x + a1.y*b1.y + a1.z*b1.z + a1.w*b1.w;
        #pragma unroll
        for (int o = 32; o >= 1; o >>= 1) {
            ssi += __shfl_xor(ssi, o);
            sst += __shfl_xor(sst, o);
            dot += __shfl_xor(dot, o);
        }
        float inv_t = rsqrtf(sst);
        ushort4 s0, s1;
        s0.x = f2bf(b0.x*inv_t); s0.y = f2bf(b0.y*inv_t);
        s0.z = f2bf(b0.z*inv_t); s0.w = f2bf(b0.w*inv_t);
        s1.x = f2bf(b1.x*inv_t); s1.y = f2bf(b1.y*inv_t);
        s1.z = f2bf(b1.z*inv_t); s1.w = f2bf(b1.w*inv_t);
        int swz = (lr & 7) << 4;
        *(ushort4*)&As[lr * 1024 + ((8 * l) ^ swz)]       = s0;
        *(ushort4*)&As[lr * 1024 + 512 + ((8 * l) ^ swz)] = s1;
        if (l == 0) {
            float inv_i = rsqrtf(ssi);
            ws[D_OFF + row] = dot * inv_i * inv_t;
        }
    }

    // ---- write G -> Bs (swizzled): gr[s] is class c = 8s + w, int4-col l
    #pragma unroll
    for (int s = 0; s < 16; ++s) {
        int c = 8 * s + w;
        *(int4*)&Bs[c * 1024 + ((l * 16) ^ ((c & 7) << 4))] = gr[s];
    }
    __syncthreads();

    // ---- MFMA: each wave computes rows 0..15 x classes [16w, 16w+16)
    f32x4 acc = {0.f, 0.f, 0.f, 0.f};
    int arow = l & 15, kq = l >> 4;
    int aswz = (arow & 7) << 4;
    int cA = 16 * w + arow;
    int aoffA = cA * 1024, aswzA = (cA & 7) << 4;
    #pragma unroll
    for (int ch = 0; ch < 16; ++ch) {
        int kb = ch * 64 + kq * 16;
        bf16x8 af = *(const bf16x8*)&As[arow * 1024 + (kb ^ aswz)];
        bf16x8 bf = *(const bf16x8*)&Bs[aoffA + (kb ^ aswzA)];
        acc = __builtin_amdgcn_mfma_f32_16x16x32_bf16(af, bf, acc, 0, 0, 0);
    }

    // ---- epilogue: S per row (16-lane reduce per wave, cross-wave via part)
    float rsum[4];
    #pragma unroll
    for (int r = 0; r < 4; ++r) {
        float s = acc[r];
        #pragma unroll
        for (int o = 1; o < 16; o <<= 1) s += __shfl_xor(s, o);
        rsum[r] = s;
    }
    if ((l & 15) == 0) {
        #pragma unroll
        for (int r = 0; r < 4; ++r) part[w][kq * 4 + r] = rsum[r];
    }
    __syncthreads();
    if (t < MT) {
        float ssum = 0.f;
        #pragma unroll
        for (int g = 0; g < 8; ++g) ssum += part[g][t];
        Ss[t] = ssum;
    }
    __syncthreads();
    float p;
    {
        float e0 = 0.f;
        #pragma unroll
        for (int r = 0; r < 4; ++r) e0 += __expf(Ss[kq * 4 + r] - acc[r]);
        p = cnts[cA] * e0;
    }
    #pragma unroll
    for (int o = 32; o >= 1; o >>= 1) p += __shfl_xor(p, o);
    if (l == 0) wred[w] = p;
    __syncthreads();
    if (t == 0) {
        float ptot = 0.f;
        #pragma unroll
        for (int g = 0; g < 8; ++g) ptot += wred[g];
        atomicAdd(ws + NEG, ptot);
        __threadfence();
        int old = atomicAdd(wsi + DONE, 1);
        sdone = (old == NBB - 1);
        if (sdone) sneg = atomicAdd(ws + NEG, 0.0f);   // coherent read-back
    }
    __syncthreads();
    if (sdone) {
        __threadfence();   // acquire before reading cross-block D
        float neg = sneg;
        float s = 0.f;
        #pragma unroll 4
        for (int i = t; i < NN; i += 512) {
            float dv = ws[D_OFF + i];
            s += logf(__expf(dv) + neg) - dv;
        }
        #pragma unroll
        for (int o = 32; o >= 1; o >>= 1) s += __shfl_xor(s, o);
        __syncthreads();
        if (l == 0) wred[w] = s;
        __syncthreads();
        if (t == 0) {
            float stot = 0.f;
            #pragma unroll
            for (int g = 0; g < 8; ++g) stot += wred[g];
            out[0] = stot;
        }
    }
}

extern "C" void kernel_launch(void* const* d_in, const int* in_sizes, int n_in,
                              void* d_out, int out_size, void* d_ws, size_t ws_size,
                              hipStream_t stream) {
    const float* img  = (const float*)d_in[0];
    const float* txt  = (const float*)d_in[1];
    const int* labels = (const int*)d_in[2];
    float* ws  = (float*)d_ws;
    float* out = (float*)d_out;

    kA<<<CP,  512, 0, stream>>>(img, labels, ws);
    kB<<<NBB, 512, 0, stream>>>(img, txt, ws, out);
}